// Round 3
// baseline (155.979 us; speedup 1.0000x reference)
//
#include <hip/hip_runtime.h>
#include <hip/hip_bf16.h>
#include <cstdint>
#include <cstddef>

// ---------------- types / helpers ----------------
typedef float  f32x4  __attribute__((ext_vector_type(4)));
typedef __bf16 bf16x8 __attribute__((ext_vector_type(8)));
typedef unsigned short u16x8 __attribute__((ext_vector_type(8)));

__device__ __forceinline__ unsigned short f2bf(float f) {
    unsigned u = __float_as_uint(f);
    u += 0x7FFFu + ((u >> 16) & 1u);   // round-to-nearest-even
    return (unsigned short)(u >> 16);
}

// ---------------- problem constants ----------------
// B=64, C=80, IN_CH=300, J=8192, S=8, OUT=1024
// feature [64,2048,14,14] (131072 rows of 196), out [64,80]

// ---------------- ws layout (bytes) ----------------
constexpr size_t OFF_FEATB = 0;          // 64*2048 bf16  = 262144
constexpr size_t OFF_ADJ   = 262144;     // 80*80 f32     = 25600
constexpr size_t OFF_Y0    = 287744;     // 80*1024 f32   = 327680
constexpr size_t OFF_X1    = 615424;     // 80*1024 f32   = 327680
constexpr size_t OFF_X2B   = 943104;     // 80*1024 bf16  = 163840
constexpr size_t OFF_WG2T  = 1106944;    // 2048*1024 f32 = 8388608
constexpr size_t OFF_XB    = 9495552;    // 80*2048 bf16  = 327680
constexpr size_t OFF_IMG   = 9823232;    // 64*8192 f32   = 2097152
constexpr size_t OFF_CLS   = 11920384;   // 80*8192 f32   = 2621440
constexpr size_t OFF_G     = 14541824;   // 80*8192 f32   = 2621440

// =================== roles (device functions) ===================

// maxpool: 16 lanes per row, 4 rows per wave, 128 rows per block of chunk.
__device__ __forceinline__ void maxpool_role(int base_row, int bid,
                                             const float* __restrict__ feature,
                                             unsigned short* __restrict__ featb) {
    int wave = threadIdx.x >> 6, lane = threadIdx.x & 63;
    int r = lane >> 4, q = lane & 15;
    #pragma unroll
    for (int it = 0; it < 4; ++it) {
        int row = base_row + bid * 128 + it * 32 + wave * 4 + r;
        const float4* p = (const float4*)(feature + (size_t)row * 196);
        float4 a = p[q], b = p[q + 16], c = p[q + 32];
        float m = fmaxf(fmaxf(fmaxf(a.x, a.y), fmaxf(a.z, a.w)),
                 fmaxf(fmaxf(fmaxf(b.x, b.y), fmaxf(b.z, b.w)),
                       fmaxf(fmaxf(c.x, c.y), fmaxf(c.z, c.w))));
        if (q == 0) {                       // tail float4 (indices 192..195)
            float4 d = p[48];
            m = fmaxf(m, fmaxf(fmaxf(d.x, d.y), fmaxf(d.z, d.w)));
        }
        #pragma unroll
        for (int off = 1; off < 16; off <<= 1) m = fmaxf(m, __shfl_xor(m, off));
        if (q == 0) featb[row] = f2bf(m);
    }
}

// skinny GEMM role: out[c, jh*512 + jq*4 ..] = sum_k X[c,k] * W[k, j]  (N=1024)
// 512 threads = 4 k-slices x 128 j-float4; LDS reduce across slices.
template <int KS>   // slice length (Kx = 4*KS)
__device__ __forceinline__ void skinny_role(int idx, const float* __restrict__ X,
                                            const float* __restrict__ W,
                                            float* __restrict__ outf,
                                            unsigned short* __restrict__ outb,
                                            int leaky, float4* red /* [4*128] */) {
    int c = idx >> 1, jh = idx & 1;
    int t = threadIdx.x;
    int jq = t & 127, ks = t >> 7;
    int j = jh * 512 + jq * 4;
    const float* xr = X + c * 4 * KS + ks * KS;
    const float* wp = W + (size_t)(ks * KS) * 1024 + j;
    float4 acc = {0.f, 0.f, 0.f, 0.f};
    #pragma unroll 5
    for (int k = 0; k < KS; k++) {
        float a = xr[k];
        float4 w = *(const float4*)(wp + (size_t)k * 1024);
        acc.x = fmaf(a, w.x, acc.x);
        acc.y = fmaf(a, w.y, acc.y);
        acc.z = fmaf(a, w.z, acc.z);
        acc.w = fmaf(a, w.w, acc.w);
    }
    red[ks * 128 + jq] = acc;
    __syncthreads();
    if (ks == 0) {
        float4 s0 = red[jq], s1 = red[128 + jq], s2 = red[256 + jq], s3 = red[384 + jq];
        float4 s;
        s.x = s0.x + s1.x + s2.x + s3.x;
        s.y = s0.y + s1.y + s2.y + s3.y;
        s.z = s0.z + s1.z + s2.z + s3.z;
        s.w = s0.w + s1.w + s2.w + s3.w;
        if (leaky) {
            if (s.x < 0.f) s.x *= 0.2f;
            if (s.y < 0.f) s.y *= 0.2f;
            if (s.z < 0.f) s.z *= 0.2f;
            if (s.w < 0.f) s.w *= 0.2f;
        }
        size_t o = (size_t)c * 1024 + j;
        if (outf) *(float4*)(outf + o) = s;
        if (outb) {
            unsigned short b4[4] = {f2bf(s.x), f2bf(s.y), f2bf(s.z), f2bf(s.w)};
            *(uint64_t*)(outb + o) = *(const uint64_t*)b4;
        }
    }
}

// transpose W_gc2 [1024][2048] -> wg2t [2048][1024], 64x64 tiles, 512 threads
__device__ __forceinline__ void transpose_role(int idx, const float* __restrict__ in,
                                               float* __restrict__ out, float* t /*64*65*/) {
    int c0 = (idx & 31) * 64, r0 = (idx >> 5) * 64;
    int tx = threadIdx.x & 63, ty = threadIdx.x >> 6;   // 64 x 8
    #pragma unroll
    for (int i = 0; i < 64; i += 8)
        t[(ty + i) * 65 + tx] = in[(size_t)(r0 + ty + i) * 2048 + c0 + tx];
    __syncthreads();
    #pragma unroll
    for (int i = 0; i < 64; i += 8)
        out[(size_t)(c0 + ty + i) * 1024 + r0 + tx] = t[tx * 65 + (ty + i)];
}

// adj[i,j] = A[j,i] * dinv[i] * dinv[j]
__device__ __forceinline__ void adj_role(const float* __restrict__ A, float* __restrict__ adjp,
                                         float* dinv /* >=80 floats LDS */) {
    int t = threadIdx.x;
    if (t < 80) {
        const float4* ar = (const float4*)(A + t * 80);
        float4 s4 = {0.f, 0.f, 0.f, 0.f};
        #pragma unroll
        for (int j = 0; j < 20; j++) {
            float4 v = ar[j];
            s4.x += v.x; s4.y += v.y; s4.z += v.z; s4.w += v.w;
        }
        dinv[t] = 1.0f / sqrtf(s4.x + s4.y + s4.z + s4.w);
    }
    __syncthreads();
    for (int i = t; i < 6400; i += 512) {
        int r = i / 80, cc = i % 80;
        adjp[i] = A[cc * 80 + r] * dinv[r] * dinv[cc];
    }
}

// MFMA GEMM with in-block K-split: out[m,n] = sum_k X[m,k]*W[n,k] (+bias[n])
// block = 8 waves: 2 n-frags x 4 k-splits; BN=32; LDS reduce; f32/bf16 out.
template <int MF>
__device__ __forceinline__ void gemm_block(int bx, const unsigned short* __restrict__ X,
                                           const float* __restrict__ W,
                                           const float* __restrict__ bias,
                                           float* __restrict__ outf,
                                           unsigned short* __restrict__ outb,
                                           int N, int K, float (*red)[64][21]) {
    int tid = threadIdx.x;
    int wave = tid >> 6, lane = tid & 63;
    int nf = wave & 1, ks = wave >> 1;
    int n = bx * 32 + nf * 16 + (lane & 15);
    int rowa = lane & 15;
    int koff = (lane >> 4) * 8;
    int Kc = K >> 2;
    int k0 = ks * Kc;

    f32x4 acc[MF];
    #pragma unroll
    for (int i = 0; i < MF; i++) acc[i] = (f32x4)(0.f);

    const float* wrow = W + (size_t)n * K;

    #pragma unroll 2
    for (int k = k0; k < k0 + Kc; k += 32) {
        float4 w0 = *(const float4*)(wrow + k + koff);
        float4 w1 = *(const float4*)(wrow + k + koff + 4);
        u16x8 bu;
        bu[0] = f2bf(w0.x); bu[1] = f2bf(w0.y); bu[2] = f2bf(w0.z); bu[3] = f2bf(w0.w);
        bu[4] = f2bf(w1.x); bu[5] = f2bf(w1.y); bu[6] = f2bf(w1.z); bu[7] = f2bf(w1.w);
        bf16x8 bf = __builtin_bit_cast(bf16x8, bu);
        #pragma unroll
        for (int mf = 0; mf < MF; mf++) {
            u16x8 au = *(const u16x8*)(X + (size_t)(mf * 16 + rowa) * K + k + koff);
            acc[mf] = __builtin_amdgcn_mfma_f32_16x16x32_bf16(
                __builtin_bit_cast(bf16x8, au), bf, acc[mf], 0, 0, 0);
        }
    }

    #pragma unroll
    for (int mf = 0; mf < MF; mf++)
        #pragma unroll
        for (int i = 0; i < 4; i++)
            red[wave][lane][mf * 4 + i] = acc[mf][i];
    __syncthreads();

    int lane2 = tid & 63, sg = (tid >> 6) & 3, nf2 = tid >> 8;
    int n2 = bx * 32 + nf2 * 16 + (lane2 & 15);
    float b = bias ? bias[n2] : 0.f;
    #pragma unroll
    for (int mf = 0; mf < MF; mf++) {
        int slot = mf * 4 + sg;
        float s = red[0 + nf2][lane2][slot] + red[2 + nf2][lane2][slot]
                + red[4 + nf2][lane2][slot] + red[6 + nf2][lane2][slot] + b;
        int row = mf * 16 + (lane2 >> 4) * 4 + sg;
        size_t o = (size_t)row * N + n2;
        if (outf) outf[o] = s;
        if (outb) outb[o] = f2bf(s);
    }
}

// =================== kernels (7 dispatches) ===================

// A: y0(160) | adj(1) | transpose(512) | maxpool chunk0 (256)  => 929 blocks
__global__ __launch_bounds__(512, 4) void kA(const float* __restrict__ inp,
                                             const float* __restrict__ W1,
                                             float* __restrict__ y0,
                                             const float* __restrict__ A,
                                             float* __restrict__ adjp,
                                             const float* __restrict__ Wg2,
                                             float* __restrict__ wg2t,
                                             const float* __restrict__ feature,
                                             unsigned short* __restrict__ featb) {
    __shared__ __align__(16) float lds[64 * 65];
    int b = blockIdx.x;
    if (b < 160)       skinny_role<75>(b, inp, W1, y0, nullptr, 0, (float4*)lds);
    else if (b < 161)  adj_role(A, adjp, lds);
    else if (b < 673)  transpose_role(b - 161, Wg2, wg2t, lds);
    else               maxpool_role(0, b - 673, feature, featb);
}

// B: x1 = leaky(adj@y0) (160) | maxpool chunk1 (256)  => 416 blocks
__global__ __launch_bounds__(512, 4) void kB(const float* __restrict__ adjp,
                                             const float* __restrict__ y0,
                                             float* __restrict__ x1,
                                             const float* __restrict__ feature,
                                             unsigned short* __restrict__ featb) {
    __shared__ __align__(16) float4 red[512];
    int b = blockIdx.x;
    if (b < 160) skinny_role<20>(b, adjp, y0, x1, nullptr, 1, red);
    else         maxpool_role(32768, b - 160, feature, featb);
}

// C: x2b = adj@x1 (bf16) (160) | maxpool chunk2 (256)  => 416 blocks
__global__ __launch_bounds__(512, 4) void kC(const float* __restrict__ adjp,
                                             const float* __restrict__ x1,
                                             unsigned short* __restrict__ x2b,
                                             const float* __restrict__ feature,
                                             unsigned short* __restrict__ featb) {
    __shared__ __align__(16) float4 red[512];
    int b = blockIdx.x;
    if (b < 160) skinny_role<20>(b, adjp, x1, nullptr, x2b, 0, red);
    else         maxpool_role(65536, b - 160, feature, featb);
}

// D: xb = x2 @ wg2t (MFMA, 64) | maxpool chunk3 (256)  => 320 blocks
__global__ __launch_bounds__(512, 4) void kD(const unsigned short* __restrict__ x2b,
                                             const float* __restrict__ wg2t,
                                             unsigned short* __restrict__ xb,
                                             const float* __restrict__ feature,
                                             unsigned short* __restrict__ featb) {
    __shared__ __align__(16) float red[8][64][21];
    int b = blockIdx.x;
    if (b < 64) gemm_block<5>(b, x2b, wg2t, nullptr, nullptr, xb, 2048, 1024, red);
    else        maxpool_role(98304, b - 64, feature, featb);
}

// E: cls = xb @ W_cls^T + b_cls  => 256 blocks
__global__ __launch_bounds__(512, 4) void kE(const unsigned short* __restrict__ xb,
                                             const float* __restrict__ W_cls,
                                             const float* __restrict__ b_cls,
                                             float* __restrict__ cls) {
    __shared__ __align__(16) float red[8][64][21];
    gemm_block<5>(blockIdx.x, xb, W_cls, b_cls, cls, nullptr, 8192, 2048, red);
}

// F: img = feat @ W_img^T + b_img (256) | G-kernel (320)  => 576 blocks
__global__ __launch_bounds__(512, 2) void kF(const unsigned short* __restrict__ featb,
                                             const float* __restrict__ W_img,
                                             const float* __restrict__ b_img,
                                             float* __restrict__ img,
                                             const float* __restrict__ cls,
                                             const float* __restrict__ W_ml,
                                             float* __restrict__ G) {
    __shared__ __align__(16) float smem[20480];   // 80 KiB, shared by both roles
    int b = blockIdx.x;
    if (b < 256) {
        gemm_block<4>(b, featb, W_img, b_img, img, nullptr, 8192, 2048,
                      (float (*)[64][21])smem);
    } else {
        // G[c2,j] = sum_c cls[c,j] * W_ml[c2, c*1024 + (j>>3)], 512 threads
        float (*wml)[80][16] = (float (*)[80][16])smem;   // [16][80][16]
        int idx = b - 256;
        int o0 = (idx & 63) * 16;
        int c2b = (idx >> 6) * 16;
        int j0 = o0 * 8;
        for (int i = threadIdx.x; i < 16 * 80 * 16; i += 512) {
            int ol = i & 15, c = (i >> 4) % 80, c2 = i / 1280;
            wml[c2][c][ol] = W_ml[(size_t)(c2b + c2) * 81920 + c * 1024 + o0 + ol];
        }
        __syncthreads();
        int jl = threadIdx.x & 127;
        int c2l = (threadIdx.x >> 7) * 4;
        int ol = jl >> 3;
        float acc[4] = {0.f, 0.f, 0.f, 0.f};
        for (int c = 0; c < 80; c++) {
            float cv = cls[(size_t)c * 8192 + j0 + jl];
            #pragma unroll
            for (int i = 0; i < 4; i++) acc[i] = fmaf(cv, wml[c2l + i][c][ol], acc[i]);
        }
        #pragma unroll
        for (int i = 0; i < 4; i++) G[(size_t)(c2b + c2l + i) * 8192 + j0 + jl] = acc[i];
    }
}

// G: out[b,c2] = sum_j img[b,j]*G[c2,j] + b_ml[c2]
__global__ __launch_bounds__(512, 4) void kG(const float* __restrict__ img,
                                             const float* __restrict__ G,
                                             const float* __restrict__ b_ml,
                                             float* __restrict__ out) {
    __shared__ float sm[8][32];
    int btile = blockIdx.x, cg = blockIdx.y;
    int kc = threadIdx.x >> 6, lane = threadIdx.x & 63;
    float acc[4][8];
    #pragma unroll
    for (int q = 0; q < 4; q++)
        #pragma unroll
        for (int i = 0; i < 8; i++) acc[q][i] = 0.f;

    #pragma unroll
    for (int step = 0; step < 4; step++) {
        int k = kc * 1024 + step * 256 + lane * 4;
        float4 gv[8];
        #pragma unroll
        for (int i = 0; i < 8; i++) gv[i] = *(const float4*)(G + (size_t)(cg * 8 + i) * 8192 + k);
        #pragma unroll
        for (int q = 0; q < 4; q++) {
            float4 iv = *(const float4*)(img + (size_t)(btile * 4 + q) * 8192 + k);
            #pragma unroll
            for (int i = 0; i < 8; i++) {
                acc[q][i] = fmaf(iv.x, gv[i].x, acc[q][i]);
                acc[q][i] = fmaf(iv.y, gv[i].y, acc[q][i]);
                acc[q][i] = fmaf(iv.z, gv[i].z, acc[q][i]);
                acc[q][i] = fmaf(iv.w, gv[i].w, acc[q][i]);
            }
        }
    }
    #pragma unroll
    for (int q = 0; q < 4; q++)
        #pragma unroll
        for (int i = 0; i < 8; i++) {
            float v = acc[q][i];
            #pragma unroll
            for (int off = 32; off; off >>= 1) v += __shfl_xor(v, off);
            if (lane == 0) sm[kc][q * 8 + i] = v;
        }
    __syncthreads();
    if (threadIdx.x < 32) {
        int i = threadIdx.x & 7;
        float s = b_ml[cg * 8 + i];
        #pragma unroll
        for (int kk = 0; kk < 8; kk++) s += sm[kk][threadIdx.x];
        int q = threadIdx.x >> 3;
        out[(size_t)(btile * 4 + q) * 80 + cg * 8 + i] = s;
    }
}

// ---------------- launch ----------------
extern "C" void kernel_launch(void* const* d_in, const int* in_sizes, int n_in,
                              void* d_out, int out_size, void* d_ws, size_t ws_size,
                              hipStream_t stream) {
    (void)in_sizes; (void)n_in; (void)out_size; (void)ws_size;
    const float* feature = (const float*)d_in[0];
    const float* inp     = (const float*)d_in[1];
    const float* A       = (const float*)d_in[2];
    const float* W_gc1   = (const float*)d_in[3];
    const float* W_gc2   = (const float*)d_in[4];
    const float* W_img   = (const float*)d_in[5];
    const float* b_img   = (const float*)d_in[6];
    const float* W_cls   = (const float*)d_in[7];
    const float* b_cls   = (const float*)d_in[8];
    const float* W_ml    = (const float*)d_in[9];
    const float* b_ml    = (const float*)d_in[10];
    float* out = (float*)d_out;
    char*  ws  = (char*)d_ws;

    unsigned short* featb = (unsigned short*)(ws + OFF_FEATB);
    float* adjp = (float*)(ws + OFF_ADJ);
    float* y0   = (float*)(ws + OFF_Y0);
    float* x1   = (float*)(ws + OFF_X1);
    unsigned short* x2b = (unsigned short*)(ws + OFF_X2B);
    float* wg2t = (float*)(ws + OFF_WG2T);
    unsigned short* xb  = (unsigned short*)(ws + OFF_XB);
    float* img  = (float*)(ws + OFF_IMG);
    float* cls  = (float*)(ws + OFF_CLS);
    float* G    = (float*)(ws + OFF_G);

    kA<<<929, 512, 0, stream>>>(inp, W_gc1, y0, A, adjp, W_gc2, wg2t, feature, featb);
    kB<<<416, 512, 0, stream>>>(adjp, y0, x1, feature, featb);
    kC<<<416, 512, 0, stream>>>(adjp, x1, x2b, feature, featb);
    kD<<<320, 512, 0, stream>>>(x2b, wg2t, xb, feature, featb);
    kE<<<256, 512, 0, stream>>>(xb, W_cls, b_cls, cls);
    kF<<<576, 512, 0, stream>>>(featb, W_img, b_img, img, cls, W_ml, G);
    kG<<<dim3(16, 10), 512, 0, stream>>>(img, G, b_ml, out);
}